// Round 14
// baseline (148.371 us; speedup 1.0000x reference)
//
#include <hip/hip_runtime.h>
#include <math.h>

// Problem constants (fixed by setup_inputs)
#define Nn 4
#define Ll 4096
#define Ss 256
#define Cc 256
#define FC 8
#define SC 32

typedef __attribute__((ext_vector_type(8))) short short8;     // 8 bf16 frag
typedef __attribute__((ext_vector_type(8))) _Float16 half8;   // 8 f16 frag
typedef __attribute__((ext_vector_type(4))) float f32x4;      // MFMA acc

__device__ __forceinline__ unsigned short f2bf(float x) {   // RTNE f32->bf16
  unsigned int u = __float_as_uint(x);
  return (unsigned short)((u + 0x7FFFu + ((u >> 16) & 1u)) >> 16);
}

// ---------------------------------------------------------------------------
// fp32-accurate f16-split on matrix cores (verified absmax 0.0078).
// ROUND-24: barrier-coupled LDS pipelines plateau at 27-35us (6 variants);
// register pipelines die on the VGPR clamp (64-100 alloc'd vs ~190 needed).
// out_mfma_k's 9us is barrier-free AND low-pressure. Synthesis: PER-WAVE
// PRIVATE LDS double-buffers -- vmcnt is per-wave state, so staging into
// private tiles needs ZERO s_barriers: each wave self-paces with vmcnt(8)
// while the next tile's 8 DMAs fly under the current KSTEP. 16KB/wave
// (2buf x (32x32 A + 32x32 B) fp32), 64KB/block -> 2 blocks/CU. A-row
// duplication between col-sharing waves is same-CU-L2-absorbed.
// Swizzle pair (verified): global source col16B = (l&7)^(l>>3); ds_read
// slot = q ^ (row&7). No lockstep, no barrier drain, no VGPR buffers.
// ---------------------------------------------------------------------------
__device__ __forceinline__ void split8v(float4 a, float4 b,
                                        half8& hi, half8& lo) {
  float v[8] = {a.x, a.y, a.z, a.w, b.x, b.y, b.z, b.w};
#pragma unroll
  for (int i = 0; i < 8; i++) {
    float x = v[i];
    _Float16 h = (_Float16)x;          // v_cvt_f16_f32 (RTNE)
    float r = (x - (float)h) * 2048.f; // exact residual, pre-scaled
    hi[i] = h;
    lo[i] = (_Float16)r;
  }
}

// stage this wave's private 32x32 A-tile + 32x32 B-tile: 8 gload_lds.
// chunk c = 8 rows; lane (lr=l>>3, l8=l&7) loads row 8c+lr, 16B-chunk
// (l8^lr) -> lands at linear LDS byte c*1024 + lane*16 (swizzled layout).
// Buf layout: floats [0,1024) = A, [1024,2048) = B.
#define STAGE(Buf, K0)                                                      \
  {                                                                         \
    _Pragma("unroll")                                                       \
    for (int c = 0; c < 4; c++) {                                           \
      const float* g = Ag + (m0w + 8 * c + lr) * Cc + (K0) + scol;          \
      __builtin_amdgcn_global_load_lds(                                     \
          (const __attribute__((address_space(1))) void*)g,                 \
          (__attribute__((address_space(3))) void*)((Buf) + c * 256),       \
          16, 0, 0);                                                        \
    }                                                                       \
    _Pragma("unroll")                                                       \
    for (int c = 0; c < 4; c++) {                                           \
      const float* g = Bg + (size_t)(n0w + 8 * c + lr) * Cc + (K0) + scol;  \
      __builtin_amdgcn_global_load_lds(                                     \
          (const __attribute__((address_space(1))) void*)g,                 \
          (__attribute__((address_space(3))) void*)((Buf) + 1024 + c * 256),\
          16, 0, 0);                                                        \
    }                                                                       \
  }

// one K=32 step on the wave's private tile: 8 ds_read_b128 (XOR-swizzled)
// + 4 splits + 12 MFMA; acc chains independent (acc1/acc2a/acc2b).
#define KSTEP(Buf)                                                          \
  {                                                                         \
    half8 Bh[2], Bl[2];                                                     \
    _Pragma("unroll")                                                       \
    for (int ni = 0; ni < 2; ni++) {                                        \
      int rw = ni * 16 + l15;                                               \
      int rb = 1024 + rw * 32, xs = rw & 7;                                 \
      float4 f0 = *(const float4*)&(Buf)[rb + (((quad * 2) ^ xs) << 2)];    \
      float4 f1 = *(const float4*)&(Buf)[rb + (((quad * 2 + 1) ^ xs) << 2)];\
      split8v(f0, f1, Bh[ni], Bl[ni]);                                      \
    }                                                                       \
    _Pragma("unroll")                                                       \
    for (int mi = 0; mi < 2; mi++) {                                        \
      int rw = mi * 16 + l15;                                               \
      int rb = rw * 32, xs = rw & 7;                                        \
      float4 f0 = *(const float4*)&(Buf)[rb + (((quad * 2) ^ xs) << 2)];    \
      float4 f1 = *(const float4*)&(Buf)[rb + (((quad * 2 + 1) ^ xs) << 2)];\
      half8 Ah, Al;                                                         \
      split8v(f0, f1, Ah, Al);                                              \
      _Pragma("unroll")                                                     \
      for (int ni = 0; ni < 2; ni++) {                                      \
        acc1[mi][ni] = __builtin_amdgcn_mfma_f32_16x16x32_f16(              \
            Ah, Bh[ni], acc1[mi][ni], 0, 0, 0);                             \
        acc2a[mi][ni] = __builtin_amdgcn_mfma_f32_16x16x32_f16(             \
            Ah, Bl[ni], acc2a[mi][ni], 0, 0, 0);                            \
        acc2b[mi][ni] = __builtin_amdgcn_mfma_f32_16x16x32_f16(             \
            Al, Bh[ni], acc2b[mi][ni], 0, 0, 0);                            \
      }                                                                     \
    }                                                                       \
  }

// ---------------------------------------------------------------------------
// Fused projections. Blocks 0..1023: xn = x0 @ W0^T + b0 (M=16384, N=256;
// 256 row-tiles x 4 col-tiles; rt=b&255 keeps a row-tile's 4 col-tiles on
// one XCD). Blocks 1024..1151: c1 = center1 @ W1^T + b1 (M=1024, N=512) +
// split/l2norm epilogue -> cpn / cval. Block 64x64, 4 waves of 32x32,
// wave w: rows (w&1)*32, cols (w>>1)*32 (n0w multiple of 32 -> one half).
// ---------------------------------------------------------------------------
__global__ __launch_bounds__(256) void proj_mfma_k(
    const float* __restrict__ x0, const float* __restrict__ W0,
    const float* __restrict__ b0, const float* __restrict__ center1,
    const float* __restrict__ W1, const float* __restrict__ b1,
    float* __restrict__ xn, float* __restrict__ cpn, float* __restrict__ cval) {
  __shared__ float P[4][2][2048];    // 64 KB: [wave][buf][A(1024)|B(1024)]
  int t = threadIdx.x;
  int wave = t >> 6, lane = t & 63;
  int quad = lane >> 4, l15 = lane & 15;
  int l8 = lane & 7, lr = lane >> 3;        // lr in [0,8)
  int scol = (l8 ^ lr) << 2;                // pre-swizzled source col (floats)
  int b = blockIdx.x;

  const float *Ag, *Bg, *bias;
  size_t m0blk;
  int n0blk;
  bool isX = (b < 1024);
  if (isX) {
    int rt = b & 255, cb = b >> 8;          // 256 row-tiles, 4 col-tiles
    m0blk = (size_t)rt * 64;
    n0blk = cb * 64;
    Ag = x0; Bg = W0; bias = b0;
  } else {
    int b2 = b - 1024;                      // 0..127
    m0blk = (size_t)(b2 >> 3) * 64;         // 16 row-tiles x 64 = 1024
    n0blk = (b2 & 7) * 64;                  // N=512
    Ag = center1; Bg = W1; bias = b1;
  }

  size_t m0w = m0blk + (size_t)(wave & 1) * 32;  // wave's 32 rows
  int n0w = n0blk + (wave >> 1) * 32;            // wave's 32 cols

  f32x4 acc1[2][2], acc2a[2][2], acc2b[2][2];
#pragma unroll
  for (int ni = 0; ni < 2; ni++) {
    float bv = bias[n0w + ni * 16 + l15];
    f32x4 ci = {bv, bv, bv, bv};
    f32x4 zz = {0.f, 0.f, 0.f, 0.f};
#pragma unroll
    for (int mi = 0; mi < 2; mi++) {
      acc1[mi][ni] = ci; acc2a[mi][ni] = zz; acc2b[mi][ni] = zz;
    }
  }

  float* B0p = &P[wave][0][0];
  float* B1p = &P[wave][1][0];
  STAGE(B0p, 0);                      // 8 outstanding
#pragma unroll 1
  for (int kt = 0; kt < 8; kt++) {
    float* cur = (kt & 1) ? B1p : B0p;
    float* nxt = (kt & 1) ? B0p : B1p;
    if (kt < 7) {
      STAGE(nxt, (kt + 1) * 32);      // 16 outstanding
      asm volatile("s_waitcnt vmcnt(8)" ::: "memory");  // kt's 8 landed
    } else {
      asm volatile("s_waitcnt vmcnt(0)" ::: "memory");
    }
    __builtin_amdgcn_sched_barrier(0);
    KSTEP(cur);                       // NO s_barrier anywhere: private tile
  }

  if (isX) {
#pragma unroll
    for (int mi = 0; mi < 2; mi++) {
#pragma unroll
      for (int reg = 0; reg < 4; reg++) {
        size_t row = m0w + mi * 16 + quad * 4 + reg;
        float* orow = xn + row * Cc + n0w;
#pragma unroll
        for (int ni = 0; ni < 2; ni++)
          orow[ni * 16 + l15] =
              acc1[mi][ni][reg] +
              (acc2a[mi][ni][reg] + acc2b[mi][ni][reg]) * (1.f / 2048.f);
      }
    }
  } else {
    int f = n0w >> 6;                  // fiber
    bool point = (n0w & 32) == 0;      // cols (n0w&63)+0..31
#pragma unroll
    for (int mi = 0; mi < 2; mi++) {
#pragma unroll
      for (int reg = 0; reg < 4; reg++) {
        int row = (int)m0w + mi * 16 + quad * 4 + reg;  // 0..1023 = nI*256+s
        int nI = row >> 8, s = row & 255;
        float v0 = acc1[mi][0][reg] +
                   (acc2a[mi][0][reg] + acc2b[mi][0][reg]) * (1.f / 2048.f);
        float v1 = acc1[mi][1][reg] +
                   (acc2a[mi][1][reg] + acc2b[mi][1][reg]) * (1.f / 2048.f);
        size_t base = (((size_t)nI * FC + f) * Ss + s) * SC;
        if (point) {
          float ss = v0 * v0 + v1 * v1;    // 2 elems/lane x 16 lanes = 32
          ss += __shfl_xor(ss, 1, 64);
          ss += __shfl_xor(ss, 2, 64);
          ss += __shfl_xor(ss, 4, 64);
          ss += __shfl_xor(ss, 8, 64);     // full row norm in every lane
          float rin = 1.f / fmaxf(sqrtf(ss), 1e-12f);
          cpn[base + l15] = v0 * rin;
          cpn[base + 16 + l15] = v1 * rin;
        } else {
          cval[base + l15] = v0;
          cval[base + 16 + l15] = v1;
        }
      }
    }
  }
}

// ---------------------------------------------------------------------------
// sim on matrix cores (round-14 structure). ROUND-24 CHANGE: dispatched is
// written as BF16 into xb (separate buffer) -- out_mfma_k converted via
// f2bf anyway, so moving the RTNE conversion here is bit-identical math
// while halving sim's store and out's A-read traffic (~17MB HBM).
// ---------------------------------------------------------------------------
__global__ __launch_bounds__(256) void sim_k(
    const float* __restrict__ xn, const float* __restrict__ cpn,
    const float* __restrict__ cval, const float* __restrict__ alphap,
    const float* __restrict__ betap, unsigned short* __restrict__ xb) {
  __shared__ half8 BhS[4][256];   // [k-quad][s] hi planes, 16 KB
  __shared__ half8 BlS[4][256];   // lo planes, 16 KB
  int t = threadIdx.x;
  int wave = t >> 6, lane = t & 63;
  int quad = lane >> 4, l15 = lane & 15;
  int lt = blockIdx.x & 63;
  int nf = blockIdx.x >> 6;        // 0..31
  int f = nf & 7, nI = nf >> 3;
  int l0 = lt * 64;
  const float* cp = cpn + (size_t)nf * Ss * SC;

  // ---- stage + split all 256 centers: thread t = center row s ----
  {
    int s = t;
    float4 va[8];
#pragma unroll
    for (int q8 = 0; q8 < 8; q8++)
      va[q8] = *(const float4*)(cp + (size_t)s * SC + q8 * 4);
#pragma unroll
    for (int q = 0; q < 4; q++) {
      half8 h, l;
      split8v(va[2 * q], va[2 * q + 1], h, l);
      BhS[q][s] = h;
      BlS[q][s] = l;
    }
  }

  // ---- A: load own row slice, l2-normalize, split ----
  half8 Ah, Al;
  {
    const float* xrow =
        xn + ((size_t)nI * Ll + l0 + wave * 16 + l15) * Cc + f * SC + quad * 8;
    float4 a0 = *(const float4*)xrow;
    float4 a1 = *(const float4*)(xrow + 4);
    float ssq = a0.x * a0.x + a0.y * a0.y + a0.z * a0.z + a0.w * a0.w +
                a1.x * a1.x + a1.y * a1.y + a1.z * a1.z + a1.w * a1.w;
    ssq += __shfl_xor(ssq, 16, 64);   // reduce across the 4 quads
    ssq += __shfl_xor(ssq, 32, 64);   // (lanes sharing l15)
    float rin = 1.f / fmaxf(sqrtf(ssq), 1e-12f);
    a0.x *= rin; a0.y *= rin; a0.z *= rin; a0.w *= rin;
    a1.x *= rin; a1.y *= rin; a1.z *= rin; a1.w *= rin;
    split8v(a0, a1, Ah, Al);
  }

  __syncthreads();   // center planes visible

  float a = alphap[0], bt = betap[0];
  float best[4];
  int bi[4];
#pragma unroll
  for (int r = 0; r < 4; r++) { best[r] = -3.0e38f; bi[r] = 0; }

  // ---- 16 s-fragments: 2 ds_read_b128 + 3 MFMA each ----
#pragma unroll
  for (int j = 0; j < 16; j++) {
    half8 bh = BhS[quad][j * 16 + l15];
    half8 bl = BlS[quad][j * 16 + l15];
    f32x4 z = {0.f, 0.f, 0.f, 0.f};
    f32x4 c1 = __builtin_amdgcn_mfma_f32_16x16x32_f16(Ah, bh, z, 0, 0, 0);
    f32x4 c2 = __builtin_amdgcn_mfma_f32_16x16x32_f16(Ah, bl, z, 0, 0, 0);
    c2 = __builtin_amdgcn_mfma_f32_16x16x32_f16(Al, bh, c2, 0, 0, 0);
    int s = j * 16 + l15;
#pragma unroll
    for (int r = 0; r < 4; r++) {
      float v = c1[r] + c2[r] * (1.f / 2048.f);
      float tv = fmaf(a, v, bt);
      if (tv > best[r]) { best[r] = tv; bi[r] = s; }
    }
  }

  // ---- cross-lane argmax (16 l15-lanes per quad), gather, write bf16 ----
#pragma unroll
  for (int r = 0; r < 4; r++) {
    float bv = best[r];
    int ix = bi[r];
#pragma unroll
    for (int m = 1; m <= 8; m <<= 1) {
      float ov = __shfl_xor(bv, m, 64);
      int oi = __shfl_xor(ix, m, 64);
      if (ov > bv || (ov == bv && oi < ix)) { bv = ov; ix = oi; }
    }
    float mv = 1.f / (1.f + expf(-bv));
    const float* cvp = cval + ((size_t)nf * Ss + ix) * SC;
    unsigned short* orow =
        xb + ((size_t)nI * Ll + l0 + wave * 16 + quad * 4 + r) * Cc + f * SC;
    orow[l15] = f2bf(cvp[l15] * mv);
    orow[l15 + 16] = f2bf(cvp[l15 + 16] * mv);
  }
}

// ---------------------------------------------------------------------------
// out = dispatched @ Wm^T + bm via bf16 MFMA, NO LDS. ROUND-24: A-operand
// read directly as bf16 from xb (no f2bf, half the read bytes).
// ---------------------------------------------------------------------------
__global__ __launch_bounds__(256) void out_mfma_k(
    const unsigned short* __restrict__ xb, const float* __restrict__ Wm,
    const float* __restrict__ bm, float* __restrict__ out) {
  int t = threadIdx.x;
  int wave = t >> 6, lane = t & 63;
  int quad = lane >> 4, l15 = lane & 15;
  size_t m0 = (size_t)(blockIdx.x >> 1) * 128 + (wave & 1) * 64;
  int n0 = (blockIdx.x & 1) * 128 + (wave >> 1) * 64;

  f32x4 acc[4][4];
#pragma unroll
  for (int ni = 0; ni < 4; ni++) {
    float bv = bm[n0 + ni * 16 + l15];
    f32x4 ci = {bv, bv, bv, bv};
#pragma unroll
    for (int mi = 0; mi < 4; mi++) acc[mi][ni] = ci;
  }

  for (int kt = 0; kt < 8; kt++) {
    int k0 = kt * 32 + quad * 8;
    short8 Af[4], Bf[4];
#pragma unroll
    for (int mi = 0; mi < 4; mi++)
      Af[mi] = *(const short8*)(xb + (m0 + mi * 16 + l15) * Cc + k0);
#pragma unroll
    for (int ni = 0; ni < 4; ni++) {
      const float* p = Wm + (size_t)(n0 + ni * 16 + l15) * Cc + k0;
      float4 lo = *(const float4*)p;
      float4 hi = *(const float4*)(p + 4);
      short8 fr;
      fr[0] = (short)f2bf(lo.x); fr[1] = (short)f2bf(lo.y);
      fr[2] = (short)f2bf(lo.z); fr[3] = (short)f2bf(lo.w);
      fr[4] = (short)f2bf(hi.x); fr[5] = (short)f2bf(hi.y);
      fr[6] = (short)f2bf(hi.z); fr[7] = (short)f2bf(hi.w);
      Bf[ni] = fr;
    }
#pragma unroll
    for (int mi = 0; mi < 4; mi++)
#pragma unroll
      for (int ni = 0; ni < 4; ni++)
        acc[mi][ni] = __builtin_amdgcn_mfma_f32_16x16x32_bf16(
            Af[mi], Bf[ni], acc[mi][ni], 0, 0, 0);
  }

#pragma unroll
  for (int mi = 0; mi < 4; mi++) {
#pragma unroll
    for (int reg = 0; reg < 4; reg++) {
      size_t row = m0 + mi * 16 + quad * 4 + reg;
      float* orow = out + row * Cc + n0;
#pragma unroll
      for (int ni = 0; ni < 4; ni++)
        orow[ni * 16 + l15] = acc[mi][ni][reg];
    }
  }
}

// ---------------------------------------------------------------------------
extern "C" void kernel_launch(void* const* d_in, const int* in_sizes, int n_in,
                              void* d_out, int out_size, void* d_ws, size_t ws_size,
                              hipStream_t stream) {
  const float* x0      = (const float*)d_in[0];
  const float* center1 = (const float*)d_in[1];
  const float* W0      = (const float*)d_in[2];
  const float* b0      = (const float*)d_in[3];
  const float* W1      = (const float*)d_in[4];
  const float* b1      = (const float*)d_in[5];
  const float* Wm      = (const float*)d_in[6];
  const float* bm      = (const float*)d_in[7];
  const float* alpha   = (const float*)d_in[8];
  const float* beta    = (const float*)d_in[9];
  float* out = (float*)d_out;
  float* ws  = (float*)d_ws;

  float* xn   = ws;                              // 16.8 MB fp32 x0p
  float* cpn  = xn + (size_t)Nn * Ll * Cc;       // 1 MB
  float* cval = cpn + (size_t)Nn * FC * Ss * SC; // 1 MB
  unsigned short* xb =
      (unsigned short*)(cval + (size_t)Nn * FC * Ss * SC);  // 8.4 MB bf16

  proj_mfma_k<<<dim3(1152), dim3(256), 0, stream>>>(
      x0, W0, b0, center1, W1, b1, xn, cpn, cval);
  sim_k<<<dim3(32 * 64), dim3(256), 0, stream>>>(xn, cpn, cval, alpha, beta, xb);
  out_mfma_k<<<dim3(256), dim3(256), 0, stream>>>(xb, Wm, bm, out);
}

// Round 15
// 138.961 us; speedup vs baseline: 1.0677x; 1.0677x over previous
//
#include <hip/hip_runtime.h>
#include <math.h>

// Problem constants (fixed by setup_inputs)
#define Nn 4
#define Ll 4096
#define Ss 256
#define Cc 256
#define FC 8
#define SC 32

typedef __attribute__((ext_vector_type(8))) short short8;     // 8 bf16 frag
typedef __attribute__((ext_vector_type(8))) _Float16 half8;   // 8 f16 frag
typedef __attribute__((ext_vector_type(4))) float f32x4;      // MFMA acc

__device__ __forceinline__ unsigned short f2bf(float x) {   // RTNE f32->bf16
  unsigned int u = __float_as_uint(x);
  return (unsigned short)((u + 0x7FFFu + ((u >> 16) & 1u)) >> 16);
}

// ---------------------------------------------------------------------------
// fp32-accurate f16-split on matrix cores (verified absmax 0.0078).
// ROUND-25: round-24's per-wave-private-LDS proj REGRESSED (+6us): private
// tiles double the gload_lds traffic (row/col-sharing waves each stage
// their own copy) and 64KB LDS halves co-residency to 2 blocks/CU.
// Pre-committed revert: proj back to the ROUND-23 MEASURED-BEST structure
// (64x64 block tile, shared dbuf LDS 32KB, 4 gloads/wave, counted
// vmcnt(4), raw s_barrier pair, launch_bounds(256,4) -> 4 blocks/CU;
// proj ~31us, total 142.8). The bf16 handoff (sim->xb->out) is KEPT --
// absmax 0.0078125 confirmed it bit-identical; this round isolates its
// delta on the best-known base.
// Swizzle pair (verified): global source col16B = (l&7)^(l>>3); ds_read
// slot = q ^ (row&7).
// ---------------------------------------------------------------------------
__device__ __forceinline__ void split8v(float4 a, float4 b,
                                        half8& hi, half8& lo) {
  float v[8] = {a.x, a.y, a.z, a.w, b.x, b.y, b.z, b.w};
#pragma unroll
  for (int i = 0; i < 8; i++) {
    float x = v[i];
    _Float16 h = (_Float16)x;          // v_cvt_f16_f32 (RTNE)
    float r = (x - (float)h) * 2048.f; // exact residual, pre-scaled
    hi[i] = h;
    lo[i] = (_Float16)r;
  }
}

// stage one 64x32 A-tile + 64x32 B-tile (fp32) into LDS, 4 gload/wave.
// chunk c = 8 rows; lane (lr=l>>3, l8=l&7) loads row 8c+lr, 16B-chunk
// (l8^lr) -> lands at linear LDS byte c*1024 + lane*16 (swizzled layout).
#define STAGE(Abuf, Bbuf, K0)                                               \
  {                                                                         \
    _Pragma("unroll")                                                       \
    for (int j = 0; j < 2; j++) {                                           \
      int c = wave * 2 + j;                                                 \
      const float* g = Ag + (m0blk + 8 * c + lr) * Cc + (K0) + scol;        \
      __builtin_amdgcn_global_load_lds(                                     \
          (const __attribute__((address_space(1))) void*)g,                 \
          (__attribute__((address_space(3))) void*)((Abuf) + c * 256),      \
          16, 0, 0);                                                        \
    }                                                                       \
    _Pragma("unroll")                                                       \
    for (int j = 0; j < 2; j++) {                                           \
      int c = wave * 2 + j;                                                 \
      const float* g =                                                      \
          Bg + (size_t)(n0blk + 8 * c + lr) * Cc + (K0) + scol;             \
      __builtin_amdgcn_global_load_lds(                                     \
          (const __attribute__((address_space(1))) void*)g,                 \
          (__attribute__((address_space(3))) void*)((Bbuf) + c * 256),      \
          16, 0, 0);                                                        \
    }                                                                       \
  }

// one K=32 step: 8 ds_read_b128 (XOR-swizzled) + 4 splits + 12 MFMA,
// all accumulator chains independent (acc1/acc2a/acc2b).
#define KSTEP(Ac, Bc)                                                       \
  {                                                                         \
    half8 Bh[2], Bl[2];                                                     \
    _Pragma("unroll")                                                       \
    for (int ni = 0; ni < 2; ni++) {                                        \
      int rw = bR0 + ni * 16 + l15;                                         \
      int rb = rw * 32, xs = rw & 7;                                        \
      float4 f0 = *(const float4*)&(Bc)[rb + (((quad * 2) ^ xs) << 2)];     \
      float4 f1 = *(const float4*)&(Bc)[rb + (((quad * 2 + 1) ^ xs) << 2)]; \
      split8v(f0, f1, Bh[ni], Bl[ni]);                                      \
    }                                                                       \
    _Pragma("unroll")                                                       \
    for (int mi = 0; mi < 2; mi++) {                                        \
      int rw = aR0 + mi * 16 + l15;                                         \
      int rb = rw * 32, xs = rw & 7;                                        \
      float4 f0 = *(const float4*)&(Ac)[rb + (((quad * 2) ^ xs) << 2)];     \
      float4 f1 = *(const float4*)&(Ac)[rb + (((quad * 2 + 1) ^ xs) << 2)]; \
      half8 Ah, Al;                                                         \
      split8v(f0, f1, Ah, Al);                                              \
      _Pragma("unroll")                                                     \
      for (int ni = 0; ni < 2; ni++) {                                      \
        acc1[mi][ni] = __builtin_amdgcn_mfma_f32_16x16x32_f16(              \
            Ah, Bh[ni], acc1[mi][ni], 0, 0, 0);                             \
        acc2a[mi][ni] = __builtin_amdgcn_mfma_f32_16x16x32_f16(             \
            Ah, Bl[ni], acc2a[mi][ni], 0, 0, 0);                            \
        acc2b[mi][ni] = __builtin_amdgcn_mfma_f32_16x16x32_f16(             \
            Al, Bh[ni], acc2b[mi][ni], 0, 0, 0);                            \
      }                                                                     \
    }                                                                       \
  }

// ---------------------------------------------------------------------------
// Fused projections. Blocks 0..1023: xn = x0 @ W0^T + b0 (M=16384, N=256;
// 256 row-tiles x 4 col-tiles; rt=b&255 keeps a row-tile's 4 col-tiles on
// one XCD). Blocks 1024..1151: c1 = center1 @ W1^T + b1 (M=1024, N=512) +
// split/l2norm epilogue -> cpn / cval. Block 64x64, 4 waves of 32x32
// (n0w multiple of 32 -> entirely in one half).
// ---------------------------------------------------------------------------
__global__ __launch_bounds__(256, 4) void proj_mfma_k(
    const float* __restrict__ x0, const float* __restrict__ W0,
    const float* __restrict__ b0, const float* __restrict__ center1,
    const float* __restrict__ W1, const float* __restrict__ b1,
    float* __restrict__ xn, float* __restrict__ cpn, float* __restrict__ cval) {
  __shared__ float As[2][64 * 32];   // 16 KB (2 x 8 KB)
  __shared__ float Bs[2][64 * 32];   // 16 KB (2 x 8 KB)
  int t = threadIdx.x;
  int wave = t >> 6, lane = t & 63;
  int quad = lane >> 4, l15 = lane & 15;
  int l8 = lane & 7, lr = lane >> 3;        // lr in [0,8)
  int scol = (l8 ^ lr) << 2;                // pre-swizzled source col (floats)
  int b = blockIdx.x;

  const float *Ag, *Bg, *bias;
  size_t m0blk;
  int n0blk;
  bool isX = (b < 1024);
  if (isX) {
    int rt = b & 255, cb = b >> 8;          // 256 row-tiles, 4 col-tiles
    m0blk = (size_t)rt * 64;
    n0blk = cb * 64;
    Ag = x0; Bg = W0; bias = b0;
  } else {
    int b2 = b - 1024;                      // 0..127
    m0blk = (size_t)(b2 >> 3) * 64;         // 16 row-tiles x 64 = 1024
    n0blk = (b2 & 7) * 64;                  // N=512
    Ag = center1; Bg = W1; bias = b1;
  }

  int aR0 = (wave & 1) * 32;                // wave's LDS A row base
  int bR0 = (wave >> 1) * 32;               // wave's LDS B row base
  int n0w = n0blk + bR0;                    // wave's output cols

  f32x4 acc1[2][2], acc2a[2][2], acc2b[2][2];
#pragma unroll
  for (int ni = 0; ni < 2; ni++) {
    float bv = bias[n0w + ni * 16 + l15];
    f32x4 ci = {bv, bv, bv, bv};
    f32x4 zz = {0.f, 0.f, 0.f, 0.f};
#pragma unroll
    for (int mi = 0; mi < 2; mi++) {
      acc1[mi][ni] = ci; acc2a[mi][ni] = zz; acc2b[mi][ni] = zz;
    }
  }

  float* Ac = &As[0][0]; float* An = &As[1][0];
  float* Bc = &Bs[0][0]; float* Bn = &Bs[1][0];
  STAGE(Ac, Bc, 0);
#pragma unroll 1
  for (int kt = 0; kt < 8; kt++) {
    if (kt < 7) {
      STAGE(An, Bn, (kt + 1) * 32);
      asm volatile("s_waitcnt vmcnt(4)" ::: "memory");  // kt's 4 landed; next 4 in flight
    } else {
      asm volatile("s_waitcnt vmcnt(0)" ::: "memory");  // epilogue drain
    }
    __builtin_amdgcn_sched_barrier(0);
    __builtin_amdgcn_s_barrier();      // RAW barrier: counted vmcnt survives
    __builtin_amdgcn_sched_barrier(0);
    KSTEP(Ac, Bc);
    asm volatile("s_waitcnt lgkmcnt(0)" ::: "memory");  // ds_reads retired
    __builtin_amdgcn_sched_barrier(0);
    __builtin_amdgcn_s_barrier();      // safe to overwrite buffers next iter
    __builtin_amdgcn_sched_barrier(0);
    float* tp;
    tp = Ac; Ac = An; An = tp;
    tp = Bc; Bc = Bn; Bn = tp;
  }

  size_t m0 = m0blk + aR0;
  if (isX) {
#pragma unroll
    for (int mi = 0; mi < 2; mi++) {
#pragma unroll
      for (int reg = 0; reg < 4; reg++) {
        size_t row = m0 + mi * 16 + quad * 4 + reg;
        float* orow = xn + row * Cc + n0w;
#pragma unroll
        for (int ni = 0; ni < 2; ni++)
          orow[ni * 16 + l15] =
              acc1[mi][ni][reg] +
              (acc2a[mi][ni][reg] + acc2b[mi][ni][reg]) * (1.f / 2048.f);
      }
    }
  } else {
    int f = n0w >> 6;                  // fiber
    bool point = (n0w & 32) == 0;      // cols (n0w&63)+0..31
#pragma unroll
    for (int mi = 0; mi < 2; mi++) {
#pragma unroll
      for (int reg = 0; reg < 4; reg++) {
        int row = (int)m0 + mi * 16 + quad * 4 + reg;  // 0..1023 = nI*256+s
        int nI = row >> 8, s = row & 255;
        float v0 = acc1[mi][0][reg] +
                   (acc2a[mi][0][reg] + acc2b[mi][0][reg]) * (1.f / 2048.f);
        float v1 = acc1[mi][1][reg] +
                   (acc2a[mi][1][reg] + acc2b[mi][1][reg]) * (1.f / 2048.f);
        size_t base = (((size_t)nI * FC + f) * Ss + s) * SC;
        if (point) {
          float ss = v0 * v0 + v1 * v1;    // 2 elems/lane x 16 lanes = 32
          ss += __shfl_xor(ss, 1, 64);
          ss += __shfl_xor(ss, 2, 64);
          ss += __shfl_xor(ss, 4, 64);
          ss += __shfl_xor(ss, 8, 64);     // full row norm in every lane
          float rin = 1.f / fmaxf(sqrtf(ss), 1e-12f);
          cpn[base + l15] = v0 * rin;
          cpn[base + 16 + l15] = v1 * rin;
        } else {
          cval[base + l15] = v0;
          cval[base + 16 + l15] = v1;
        }
      }
    }
  }
}

// ---------------------------------------------------------------------------
// sim on matrix cores (round-14 structure). Dispatched written as BF16
// into xb -- out_mfma_k converted via f2bf anyway, so the RTNE conversion
// here is bit-identical math while halving sim-store / out-read traffic.
// ---------------------------------------------------------------------------
__global__ __launch_bounds__(256) void sim_k(
    const float* __restrict__ xn, const float* __restrict__ cpn,
    const float* __restrict__ cval, const float* __restrict__ alphap,
    const float* __restrict__ betap, unsigned short* __restrict__ xb) {
  __shared__ half8 BhS[4][256];   // [k-quad][s] hi planes, 16 KB
  __shared__ half8 BlS[4][256];   // lo planes, 16 KB
  int t = threadIdx.x;
  int wave = t >> 6, lane = t & 63;
  int quad = lane >> 4, l15 = lane & 15;
  int lt = blockIdx.x & 63;
  int nf = blockIdx.x >> 6;        // 0..31
  int f = nf & 7, nI = nf >> 3;
  int l0 = lt * 64;
  const float* cp = cpn + (size_t)nf * Ss * SC;

  // ---- stage + split all 256 centers: thread t = center row s ----
  {
    int s = t;
    float4 va[8];
#pragma unroll
    for (int q8 = 0; q8 < 8; q8++)
      va[q8] = *(const float4*)(cp + (size_t)s * SC + q8 * 4);
#pragma unroll
    for (int q = 0; q < 4; q++) {
      half8 h, l;
      split8v(va[2 * q], va[2 * q + 1], h, l);
      BhS[q][s] = h;
      BlS[q][s] = l;
    }
  }

  // ---- A: load own row slice, l2-normalize, split ----
  half8 Ah, Al;
  {
    const float* xrow =
        xn + ((size_t)nI * Ll + l0 + wave * 16 + l15) * Cc + f * SC + quad * 8;
    float4 a0 = *(const float4*)xrow;
    float4 a1 = *(const float4*)(xrow + 4);
    float ssq = a0.x * a0.x + a0.y * a0.y + a0.z * a0.z + a0.w * a0.w +
                a1.x * a1.x + a1.y * a1.y + a1.z * a1.z + a1.w * a1.w;
    ssq += __shfl_xor(ssq, 16, 64);   // reduce across the 4 quads
    ssq += __shfl_xor(ssq, 32, 64);   // (lanes sharing l15)
    float rin = 1.f / fmaxf(sqrtf(ssq), 1e-12f);
    a0.x *= rin; a0.y *= rin; a0.z *= rin; a0.w *= rin;
    a1.x *= rin; a1.y *= rin; a1.z *= rin; a1.w *= rin;
    split8v(a0, a1, Ah, Al);
  }

  __syncthreads();   // center planes visible

  float a = alphap[0], bt = betap[0];
  float best[4];
  int bi[4];
#pragma unroll
  for (int r = 0; r < 4; r++) { best[r] = -3.0e38f; bi[r] = 0; }

  // ---- 16 s-fragments: 2 ds_read_b128 + 3 MFMA each ----
#pragma unroll
  for (int j = 0; j < 16; j++) {
    half8 bh = BhS[quad][j * 16 + l15];
    half8 bl = BlS[quad][j * 16 + l15];
    f32x4 z = {0.f, 0.f, 0.f, 0.f};
    f32x4 c1 = __builtin_amdgcn_mfma_f32_16x16x32_f16(Ah, bh, z, 0, 0, 0);
    f32x4 c2 = __builtin_amdgcn_mfma_f32_16x16x32_f16(Ah, bl, z, 0, 0, 0);
    c2 = __builtin_amdgcn_mfma_f32_16x16x32_f16(Al, bh, c2, 0, 0, 0);
    int s = j * 16 + l15;
#pragma unroll
    for (int r = 0; r < 4; r++) {
      float v = c1[r] + c2[r] * (1.f / 2048.f);
      float tv = fmaf(a, v, bt);
      if (tv > best[r]) { best[r] = tv; bi[r] = s; }
    }
  }

  // ---- cross-lane argmax (16 l15-lanes per quad), gather, write bf16 ----
#pragma unroll
  for (int r = 0; r < 4; r++) {
    float bv = best[r];
    int ix = bi[r];
#pragma unroll
    for (int m = 1; m <= 8; m <<= 1) {
      float ov = __shfl_xor(bv, m, 64);
      int oi = __shfl_xor(ix, m, 64);
      if (ov > bv || (ov == bv && oi < ix)) { bv = ov; ix = oi; }
    }
    float mv = 1.f / (1.f + expf(-bv));
    const float* cvp = cval + ((size_t)nf * Ss + ix) * SC;
    unsigned short* orow =
        xb + ((size_t)nI * Ll + l0 + wave * 16 + quad * 4 + r) * Cc + f * SC;
    orow[l15] = f2bf(cvp[l15] * mv);
    orow[l15 + 16] = f2bf(cvp[l15 + 16] * mv);
  }
}

// ---------------------------------------------------------------------------
// out = dispatched @ Wm^T + bm via bf16 MFMA, NO LDS. A-operand read
// directly as bf16 from xb (no f2bf, half the read bytes).
// ---------------------------------------------------------------------------
__global__ __launch_bounds__(256) void out_mfma_k(
    const unsigned short* __restrict__ xb, const float* __restrict__ Wm,
    const float* __restrict__ bm, float* __restrict__ out) {
  int t = threadIdx.x;
  int wave = t >> 6, lane = t & 63;
  int quad = lane >> 4, l15 = lane & 15;
  size_t m0 = (size_t)(blockIdx.x >> 1) * 128 + (wave & 1) * 64;
  int n0 = (blockIdx.x & 1) * 128 + (wave >> 1) * 64;

  f32x4 acc[4][4];
#pragma unroll
  for (int ni = 0; ni < 4; ni++) {
    float bv = bm[n0 + ni * 16 + l15];
    f32x4 ci = {bv, bv, bv, bv};
#pragma unroll
    for (int mi = 0; mi < 4; mi++) acc[mi][ni] = ci;
  }

  for (int kt = 0; kt < 8; kt++) {
    int k0 = kt * 32 + quad * 8;
    short8 Af[4], Bf[4];
#pragma unroll
    for (int mi = 0; mi < 4; mi++)
      Af[mi] = *(const short8*)(xb + (m0 + mi * 16 + l15) * Cc + k0);
#pragma unroll
    for (int ni = 0; ni < 4; ni++) {
      const float* p = Wm + (size_t)(n0 + ni * 16 + l15) * Cc + k0;
      float4 lo = *(const float4*)p;
      float4 hi = *(const float4*)(p + 4);
      short8 fr;
      fr[0] = (short)f2bf(lo.x); fr[1] = (short)f2bf(lo.y);
      fr[2] = (short)f2bf(lo.z); fr[3] = (short)f2bf(lo.w);
      fr[4] = (short)f2bf(hi.x); fr[5] = (short)f2bf(hi.y);
      fr[6] = (short)f2bf(hi.z); fr[7] = (short)f2bf(hi.w);
      Bf[ni] = fr;
    }
#pragma unroll
    for (int mi = 0; mi < 4; mi++)
#pragma unroll
      for (int ni = 0; ni < 4; ni++)
        acc[mi][ni] = __builtin_amdgcn_mfma_f32_16x16x32_bf16(
            Af[mi], Bf[ni], acc[mi][ni], 0, 0, 0);
  }

#pragma unroll
  for (int mi = 0; mi < 4; mi++) {
#pragma unroll
    for (int reg = 0; reg < 4; reg++) {
      size_t row = m0 + mi * 16 + quad * 4 + reg;
      float* orow = out + row * Cc + n0;
#pragma unroll
      for (int ni = 0; ni < 4; ni++)
        orow[ni * 16 + l15] = acc[mi][ni][reg];
    }
  }
}

// ---------------------------------------------------------------------------
extern "C" void kernel_launch(void* const* d_in, const int* in_sizes, int n_in,
                              void* d_out, int out_size, void* d_ws, size_t ws_size,
                              hipStream_t stream) {
  const float* x0      = (const float*)d_in[0];
  const float* center1 = (const float*)d_in[1];
  const float* W0      = (const float*)d_in[2];
  const float* b0      = (const float*)d_in[3];
  const float* W1      = (const float*)d_in[4];
  const float* b1      = (const float*)d_in[5];
  const float* Wm      = (const float*)d_in[6];
  const float* bm      = (const float*)d_in[7];
  const float* alpha   = (const float*)d_in[8];
  const float* beta    = (const float*)d_in[9];
  float* out = (float*)d_out;
  float* ws  = (float*)d_ws;

  float* xn   = ws;                              // 16.8 MB fp32 x0p
  float* cpn  = xn + (size_t)Nn * Ll * Cc;       // 1 MB
  float* cval = cpn + (size_t)Nn * FC * Ss * SC; // 1 MB
  unsigned short* xb =
      (unsigned short*)(cval + (size_t)Nn * FC * Ss * SC);  // 8.4 MB bf16

  proj_mfma_k<<<dim3(1152), dim3(256), 0, stream>>>(
      x0, W0, b0, center1, W1, b1, xn, cpn, cval);
  sim_k<<<dim3(32 * 64), dim3(256), 0, stream>>>(xn, cpn, cval, alpha, beta, xb);
  out_mfma_k<<<dim3(256), dim3(256), 0, stream>>>(xb, Wm, bm, out);
}

// Round 16
// 136.961 us; speedup vs baseline: 1.0833x; 1.0146x over previous
//
#include <hip/hip_runtime.h>
#include <math.h>

// Problem constants (fixed by setup_inputs)
#define Nn 4
#define Ll 4096
#define Ss 256
#define Cc 256
#define FC 8
#define SC 32

typedef __attribute__((ext_vector_type(8))) short short8;     // 8 bf16 frag
typedef __attribute__((ext_vector_type(8))) _Float16 half8;   // 8 f16 frag
typedef __attribute__((ext_vector_type(4))) float f32x4;      // MFMA acc

__device__ __forceinline__ unsigned short f2bf(float x) {   // RTNE f32->bf16
  unsigned int u = __float_as_uint(x);
  return (unsigned short)((u + 0x7FFFu + ((u >> 16) & 1u)) >> 16);
}

// ---------------------------------------------------------------------------
// fp32-accurate f16-split on matrix cores (verified absmax 0.0078).
// ROUND-26: best=138.96us (r25: revert + bf16 handoff, handoff ~ -4us).
// proj ~31us vs ~7us overlapped floor. Latency ledger: the awaited tile's
// DMA was issued only ONE KSTEP (~350cy) earlier, but gload_lds completion
// is ~600-900cy -> each of the 8 iters exposes ~300-500cy. Fix: TRIPLE
// buffer (pipeline depth 2) -- awaited tile was issued TWO KSTEPs (~700cy)
// ago. vmcnt ledger (4 DMAs/wave/tile): prologue tiles 0,1 (8 out);
// iter kt stages kt+2 (12 out) then vmcnt(8) retires tile kt; kt=6 ->
// vmcnt(4); kt=7 -> vmcnt(0). STAGE(kt+2) writes the buffer read at
// KSTEP(kt-1), protected by iter kt-1's barrier-2. LDS 32->48KB, 3
// blocks/CU (launch_bounds(256,3)): trade 1 block TLP for zero exposed
// DMA latency. Swizzle pair (verified): source col16B = (l&7)^(l>>3);
// ds_read slot = q ^ (row&7).
// ---------------------------------------------------------------------------
__device__ __forceinline__ void split8v(float4 a, float4 b,
                                        half8& hi, half8& lo) {
  float v[8] = {a.x, a.y, a.z, a.w, b.x, b.y, b.z, b.w};
#pragma unroll
  for (int i = 0; i < 8; i++) {
    float x = v[i];
    _Float16 h = (_Float16)x;          // v_cvt_f16_f32 (RTNE)
    float r = (x - (float)h) * 2048.f; // exact residual, pre-scaled
    hi[i] = h;
    lo[i] = (_Float16)r;
  }
}

// stage one 64x32 A-tile + 64x32 B-tile (fp32) into LDS, 4 gload/wave.
// chunk c = 8 rows; lane (lr=l>>3, l8=l&7) loads row 8c+lr, 16B-chunk
// (l8^lr) -> lands at linear LDS byte c*1024 + lane*16 (swizzled layout).
#define STAGE(Abuf, Bbuf, K0)                                               \
  {                                                                         \
    _Pragma("unroll")                                                       \
    for (int j = 0; j < 2; j++) {                                           \
      int c = wave * 2 + j;                                                 \
      const float* g = Ag + (m0blk + 8 * c + lr) * Cc + (K0) + scol;        \
      __builtin_amdgcn_global_load_lds(                                     \
          (const __attribute__((address_space(1))) void*)g,                 \
          (__attribute__((address_space(3))) void*)((Abuf) + c * 256),      \
          16, 0, 0);                                                        \
    }                                                                       \
    _Pragma("unroll")                                                       \
    for (int j = 0; j < 2; j++) {                                           \
      int c = wave * 2 + j;                                                 \
      const float* g =                                                      \
          Bg + (size_t)(n0blk + 8 * c + lr) * Cc + (K0) + scol;             \
      __builtin_amdgcn_global_load_lds(                                     \
          (const __attribute__((address_space(1))) void*)g,                 \
          (__attribute__((address_space(3))) void*)((Bbuf) + c * 256),      \
          16, 0, 0);                                                        \
    }                                                                       \
  }

// one K=32 step: 8 ds_read_b128 (XOR-swizzled) + 4 splits + 12 MFMA,
// all accumulator chains independent (acc1/acc2a/acc2b).
#define KSTEP(Ac, Bc)                                                       \
  {                                                                         \
    half8 Bh[2], Bl[2];                                                     \
    _Pragma("unroll")                                                       \
    for (int ni = 0; ni < 2; ni++) {                                        \
      int rw = bR0 + ni * 16 + l15;                                         \
      int rb = rw * 32, xs = rw & 7;                                        \
      float4 f0 = *(const float4*)&(Bc)[rb + (((quad * 2) ^ xs) << 2)];     \
      float4 f1 = *(const float4*)&(Bc)[rb + (((quad * 2 + 1) ^ xs) << 2)]; \
      split8v(f0, f1, Bh[ni], Bl[ni]);                                      \
    }                                                                       \
    _Pragma("unroll")                                                       \
    for (int mi = 0; mi < 2; mi++) {                                        \
      int rw = aR0 + mi * 16 + l15;                                         \
      int rb = rw * 32, xs = rw & 7;                                        \
      float4 f0 = *(const float4*)&(Ac)[rb + (((quad * 2) ^ xs) << 2)];     \
      float4 f1 = *(const float4*)&(Ac)[rb + (((quad * 2 + 1) ^ xs) << 2)]; \
      half8 Ah, Al;                                                         \
      split8v(f0, f1, Ah, Al);                                              \
      _Pragma("unroll")                                                     \
      for (int ni = 0; ni < 2; ni++) {                                      \
        acc1[mi][ni] = __builtin_amdgcn_mfma_f32_16x16x32_f16(              \
            Ah, Bh[ni], acc1[mi][ni], 0, 0, 0);                             \
        acc2a[mi][ni] = __builtin_amdgcn_mfma_f32_16x16x32_f16(             \
            Ah, Bl[ni], acc2a[mi][ni], 0, 0, 0);                            \
        acc2b[mi][ni] = __builtin_amdgcn_mfma_f32_16x16x32_f16(             \
            Al, Bh[ni], acc2b[mi][ni], 0, 0, 0);                            \
      }                                                                     \
    }                                                                       \
  }

// ---------------------------------------------------------------------------
// Fused projections. Blocks 0..1023: xn = x0 @ W0^T + b0 (M=16384, N=256;
// 256 row-tiles x 4 col-tiles; rt=b&255 keeps a row-tile's 4 col-tiles on
// one XCD). Blocks 1024..1151: c1 = center1 @ W1^T + b1 (M=1024, N=512) +
// split/l2norm epilogue -> cpn / cval. Block 64x64, 4 waves of 32x32
// (n0w multiple of 32 -> entirely in one half).
// ---------------------------------------------------------------------------
__global__ __launch_bounds__(256, 3) void proj_mfma_k(
    const float* __restrict__ x0, const float* __restrict__ W0,
    const float* __restrict__ b0, const float* __restrict__ center1,
    const float* __restrict__ W1, const float* __restrict__ b1,
    float* __restrict__ xn, float* __restrict__ cpn, float* __restrict__ cval) {
  __shared__ float As[3][64 * 32];   // 24 KB (3 x 8 KB)
  __shared__ float Bs[3][64 * 32];   // 24 KB (3 x 8 KB)
  int t = threadIdx.x;
  int wave = t >> 6, lane = t & 63;
  int quad = lane >> 4, l15 = lane & 15;
  int l8 = lane & 7, lr = lane >> 3;        // lr in [0,8)
  int scol = (l8 ^ lr) << 2;                // pre-swizzled source col (floats)
  int b = blockIdx.x;

  const float *Ag, *Bg, *bias;
  size_t m0blk;
  int n0blk;
  bool isX = (b < 1024);
  if (isX) {
    int rt = b & 255, cb = b >> 8;          // 256 row-tiles, 4 col-tiles
    m0blk = (size_t)rt * 64;
    n0blk = cb * 64;
    Ag = x0; Bg = W0; bias = b0;
  } else {
    int b2 = b - 1024;                      // 0..127
    m0blk = (size_t)(b2 >> 3) * 64;         // 16 row-tiles x 64 = 1024
    n0blk = (b2 & 7) * 64;                  // N=512
    Ag = center1; Bg = W1; bias = b1;
  }

  int aR0 = (wave & 1) * 32;                // wave's LDS A row base
  int bR0 = (wave >> 1) * 32;               // wave's LDS B row base
  int n0w = n0blk + bR0;                    // wave's output cols

  f32x4 acc1[2][2], acc2a[2][2], acc2b[2][2];
#pragma unroll
  for (int ni = 0; ni < 2; ni++) {
    float bv = bias[n0w + ni * 16 + l15];
    f32x4 ci = {bv, bv, bv, bv};
    f32x4 zz = {0.f, 0.f, 0.f, 0.f};
#pragma unroll
    for (int mi = 0; mi < 2; mi++) {
      acc1[mi][ni] = ci; acc2a[mi][ni] = zz; acc2b[mi][ni] = zz;
    }
  }

  // R = tile kt (read now), F = tile kt+1 (in flight), S = stage kt+2.
  float* AR = &As[0][0]; float* AF = &As[1][0]; float* AS = &As[2][0];
  float* BR = &Bs[0][0]; float* BF = &Bs[1][0]; float* BS = &Bs[2][0];
  STAGE(AR, BR, 0);                   // 4 outstanding
  STAGE(AF, BF, 32);                  // 8 outstanding
#pragma unroll 1
  for (int kt = 0; kt < 8; kt++) {
    if (kt < 6) {
      STAGE(AS, BS, (kt + 2) * 32);   // 12 outstanding
      asm volatile("s_waitcnt vmcnt(8)" ::: "memory");  // tile kt landed
    } else if (kt == 6) {
      asm volatile("s_waitcnt vmcnt(4)" ::: "memory");  // tile 6 landed
    } else {
      asm volatile("s_waitcnt vmcnt(0)" ::: "memory");  // tile 7 landed
    }
    __builtin_amdgcn_sched_barrier(0);
    __builtin_amdgcn_s_barrier();      // RAW barrier: counted vmcnt survives
    __builtin_amdgcn_sched_barrier(0);
    KSTEP(AR, BR);
    asm volatile("s_waitcnt lgkmcnt(0)" ::: "memory");  // ds_reads retired
    __builtin_amdgcn_sched_barrier(0);
    __builtin_amdgcn_s_barrier();      // safe to overwrite R next iters
    __builtin_amdgcn_sched_barrier(0);
    float* tp;
    tp = AR; AR = AF; AF = AS; AS = tp;   // rotate triple buffer
    tp = BR; BR = BF; BF = BS; BS = tp;
  }

  size_t m0 = m0blk + aR0;
  if (isX) {
#pragma unroll
    for (int mi = 0; mi < 2; mi++) {
#pragma unroll
      for (int reg = 0; reg < 4; reg++) {
        size_t row = m0 + mi * 16 + quad * 4 + reg;
        float* orow = xn + row * Cc + n0w;
#pragma unroll
        for (int ni = 0; ni < 2; ni++)
          orow[ni * 16 + l15] =
              acc1[mi][ni][reg] +
              (acc2a[mi][ni][reg] + acc2b[mi][ni][reg]) * (1.f / 2048.f);
      }
    }
  } else {
    int f = n0w >> 6;                  // fiber
    bool point = (n0w & 32) == 0;      // cols (n0w&63)+0..31
#pragma unroll
    for (int mi = 0; mi < 2; mi++) {
#pragma unroll
      for (int reg = 0; reg < 4; reg++) {
        int row = (int)m0 + mi * 16 + quad * 4 + reg;  // 0..1023 = nI*256+s
        int nI = row >> 8, s = row & 255;
        float v0 = acc1[mi][0][reg] +
                   (acc2a[mi][0][reg] + acc2b[mi][0][reg]) * (1.f / 2048.f);
        float v1 = acc1[mi][1][reg] +
                   (acc2a[mi][1][reg] + acc2b[mi][1][reg]) * (1.f / 2048.f);
        size_t base = (((size_t)nI * FC + f) * Ss + s) * SC;
        if (point) {
          float ss = v0 * v0 + v1 * v1;    // 2 elems/lane x 16 lanes = 32
          ss += __shfl_xor(ss, 1, 64);
          ss += __shfl_xor(ss, 2, 64);
          ss += __shfl_xor(ss, 4, 64);
          ss += __shfl_xor(ss, 8, 64);     // full row norm in every lane
          float rin = 1.f / fmaxf(sqrtf(ss), 1e-12f);
          cpn[base + l15] = v0 * rin;
          cpn[base + 16 + l15] = v1 * rin;
        } else {
          cval[base + l15] = v0;
          cval[base + 16 + l15] = v1;
        }
      }
    }
  }
}

// ---------------------------------------------------------------------------
// sim on matrix cores (round-14 structure). Dispatched written as BF16
// into xb -- out_mfma_k converted via f2bf anyway, so the RTNE conversion
// here is bit-identical math while halving sim-store / out-read traffic.
// ---------------------------------------------------------------------------
__global__ __launch_bounds__(256) void sim_k(
    const float* __restrict__ xn, const float* __restrict__ cpn,
    const float* __restrict__ cval, const float* __restrict__ alphap,
    const float* __restrict__ betap, unsigned short* __restrict__ xb) {
  __shared__ half8 BhS[4][256];   // [k-quad][s] hi planes, 16 KB
  __shared__ half8 BlS[4][256];   // lo planes, 16 KB
  int t = threadIdx.x;
  int wave = t >> 6, lane = t & 63;
  int quad = lane >> 4, l15 = lane & 15;
  int lt = blockIdx.x & 63;
  int nf = blockIdx.x >> 6;        // 0..31
  int f = nf & 7, nI = nf >> 3;
  int l0 = lt * 64;
  const float* cp = cpn + (size_t)nf * Ss * SC;

  // ---- stage + split all 256 centers: thread t = center row s ----
  {
    int s = t;
    float4 va[8];
#pragma unroll
    for (int q8 = 0; q8 < 8; q8++)
      va[q8] = *(const float4*)(cp + (size_t)s * SC + q8 * 4);
#pragma unroll
    for (int q = 0; q < 4; q++) {
      half8 h, l;
      split8v(va[2 * q], va[2 * q + 1], h, l);
      BhS[q][s] = h;
      BlS[q][s] = l;
    }
  }

  // ---- A: load own row slice, l2-normalize, split ----
  half8 Ah, Al;
  {
    const float* xrow =
        xn + ((size_t)nI * Ll + l0 + wave * 16 + l15) * Cc + f * SC + quad * 8;
    float4 a0 = *(const float4*)xrow;
    float4 a1 = *(const float4*)(xrow + 4);
    float ssq = a0.x * a0.x + a0.y * a0.y + a0.z * a0.z + a0.w * a0.w +
                a1.x * a1.x + a1.y * a1.y + a1.z * a1.z + a1.w * a1.w;
    ssq += __shfl_xor(ssq, 16, 64);   // reduce across the 4 quads
    ssq += __shfl_xor(ssq, 32, 64);   // (lanes sharing l15)
    float rin = 1.f / fmaxf(sqrtf(ssq), 1e-12f);
    a0.x *= rin; a0.y *= rin; a0.z *= rin; a0.w *= rin;
    a1.x *= rin; a1.y *= rin; a1.z *= rin; a1.w *= rin;
    split8v(a0, a1, Ah, Al);
  }

  __syncthreads();   // center planes visible

  float a = alphap[0], bt = betap[0];
  float best[4];
  int bi[4];
#pragma unroll
  for (int r = 0; r < 4; r++) { best[r] = -3.0e38f; bi[r] = 0; }

  // ---- 16 s-fragments: 2 ds_read_b128 + 3 MFMA each ----
#pragma unroll
  for (int j = 0; j < 16; j++) {
    half8 bh = BhS[quad][j * 16 + l15];
    half8 bl = BlS[quad][j * 16 + l15];
    f32x4 z = {0.f, 0.f, 0.f, 0.f};
    f32x4 c1 = __builtin_amdgcn_mfma_f32_16x16x32_f16(Ah, bh, z, 0, 0, 0);
    f32x4 c2 = __builtin_amdgcn_mfma_f32_16x16x32_f16(Ah, bl, z, 0, 0, 0);
    c2 = __builtin_amdgcn_mfma_f32_16x16x32_f16(Al, bh, c2, 0, 0, 0);
    int s = j * 16 + l15;
#pragma unroll
    for (int r = 0; r < 4; r++) {
      float v = c1[r] + c2[r] * (1.f / 2048.f);
      float tv = fmaf(a, v, bt);
      if (tv > best[r]) { best[r] = tv; bi[r] = s; }
    }
  }

  // ---- cross-lane argmax (16 l15-lanes per quad), gather, write bf16 ----
#pragma unroll
  for (int r = 0; r < 4; r++) {
    float bv = best[r];
    int ix = bi[r];
#pragma unroll
    for (int m = 1; m <= 8; m <<= 1) {
      float ov = __shfl_xor(bv, m, 64);
      int oi = __shfl_xor(ix, m, 64);
      if (ov > bv || (ov == bv && oi < ix)) { bv = ov; ix = oi; }
    }
    float mv = 1.f / (1.f + expf(-bv));
    const float* cvp = cval + ((size_t)nf * Ss + ix) * SC;
    unsigned short* orow =
        xb + ((size_t)nI * Ll + l0 + wave * 16 + quad * 4 + r) * Cc + f * SC;
    orow[l15] = f2bf(cvp[l15] * mv);
    orow[l15 + 16] = f2bf(cvp[l15 + 16] * mv);
  }
}

// ---------------------------------------------------------------------------
// out = dispatched @ Wm^T + bm via bf16 MFMA, NO LDS. A-operand read
// directly as bf16 from xb (no f2bf, half the read bytes).
// ---------------------------------------------------------------------------
__global__ __launch_bounds__(256) void out_mfma_k(
    const unsigned short* __restrict__ xb, const float* __restrict__ Wm,
    const float* __restrict__ bm, float* __restrict__ out) {
  int t = threadIdx.x;
  int wave = t >> 6, lane = t & 63;
  int quad = lane >> 4, l15 = lane & 15;
  size_t m0 = (size_t)(blockIdx.x >> 1) * 128 + (wave & 1) * 64;
  int n0 = (blockIdx.x & 1) * 128 + (wave >> 1) * 64;

  f32x4 acc[4][4];
#pragma unroll
  for (int ni = 0; ni < 4; ni++) {
    float bv = bm[n0 + ni * 16 + l15];
    f32x4 ci = {bv, bv, bv, bv};
#pragma unroll
    for (int mi = 0; mi < 4; mi++) acc[mi][ni] = ci;
  }

  for (int kt = 0; kt < 8; kt++) {
    int k0 = kt * 32 + quad * 8;
    short8 Af[4], Bf[4];
#pragma unroll
    for (int mi = 0; mi < 4; mi++)
      Af[mi] = *(const short8*)(xb + (m0 + mi * 16 + l15) * Cc + k0);
#pragma unroll
    for (int ni = 0; ni < 4; ni++) {
      const float* p = Wm + (size_t)(n0 + ni * 16 + l15) * Cc + k0;
      float4 lo = *(const float4*)p;
      float4 hi = *(const float4*)(p + 4);
      short8 fr;
      fr[0] = (short)f2bf(lo.x); fr[1] = (short)f2bf(lo.y);
      fr[2] = (short)f2bf(lo.z); fr[3] = (short)f2bf(lo.w);
      fr[4] = (short)f2bf(hi.x); fr[5] = (short)f2bf(hi.y);
      fr[6] = (short)f2bf(hi.z); fr[7] = (short)f2bf(hi.w);
      Bf[ni] = fr;
    }
#pragma unroll
    for (int mi = 0; mi < 4; mi++)
#pragma unroll
      for (int ni = 0; ni < 4; ni++)
        acc[mi][ni] = __builtin_amdgcn_mfma_f32_16x16x32_bf16(
            Af[mi], Bf[ni], acc[mi][ni], 0, 0, 0);
  }

#pragma unroll
  for (int mi = 0; mi < 4; mi++) {
#pragma unroll
    for (int reg = 0; reg < 4; reg++) {
      size_t row = m0 + mi * 16 + quad * 4 + reg;
      float* orow = out + row * Cc + n0;
#pragma unroll
      for (int ni = 0; ni < 4; ni++)
        orow[ni * 16 + l15] = acc[mi][ni][reg];
    }
  }
}

// ---------------------------------------------------------------------------
extern "C" void kernel_launch(void* const* d_in, const int* in_sizes, int n_in,
                              void* d_out, int out_size, void* d_ws, size_t ws_size,
                              hipStream_t stream) {
  const float* x0      = (const float*)d_in[0];
  const float* center1 = (const float*)d_in[1];
  const float* W0      = (const float*)d_in[2];
  const float* b0      = (const float*)d_in[3];
  const float* W1      = (const float*)d_in[4];
  const float* b1      = (const float*)d_in[5];
  const float* Wm      = (const float*)d_in[6];
  const float* bm      = (const float*)d_in[7];
  const float* alpha   = (const float*)d_in[8];
  const float* beta    = (const float*)d_in[9];
  float* out = (float*)d_out;
  float* ws  = (float*)d_ws;

  float* xn   = ws;                              // 16.8 MB fp32 x0p
  float* cpn  = xn + (size_t)Nn * Ll * Cc;       // 1 MB
  float* cval = cpn + (size_t)Nn * FC * Ss * SC; // 1 MB
  unsigned short* xb =
      (unsigned short*)(cval + (size_t)Nn * FC * Ss * SC);  // 8.4 MB bf16

  proj_mfma_k<<<dim3(1152), dim3(256), 0, stream>>>(
      x0, W0, b0, center1, W1, b1, xn, cpn, cval);
  sim_k<<<dim3(32 * 64), dim3(256), 0, stream>>>(xn, cpn, cval, alpha, beta, xb);
  out_mfma_k<<<dim3(256), dim3(256), 0, stream>>>(xb, Wm, bm, out);
}